// Round 5
// baseline (738.880 us; speedup 1.0000x reference)
//
#include <hip/hip_runtime.h>
#include <hip/hip_bf16.h>

#define E_DIM 1024
#define HDIM  2730
#define HP    2752   // H padded to 64 (hbuf row width, gemm2 K: 43*64)
#define HP2   2816   // H padded to 128 (gemm1 n-tiles: 22*128)
#define NEXP  8
#define NTOK  4096
#define NPAIR 8192
#define NSLOT 72     // max m-tiles of 128 over all experts (<=71) + pad
#define LN_EPS 1e-5f

typedef __attribute__((ext_vector_type(8)))  short short8;
typedef __attribute__((ext_vector_type(4)))  short short4v;
typedef __attribute__((ext_vector_type(4)))  float floatx4;
typedef __attribute__((ext_vector_type(16))) float floatx16;
typedef __attribute__((ext_vector_type(4)))  int   intx4;

__device__ __forceinline__ __hip_bfloat16 f2bf(float f) { return __float2bfloat16(f); }

// ---------------- router: fp32 logits, top-2, softmax weights ----------------
__global__ __launch_bounds__(256) void router_k(const float* __restrict__ x,
    const float* __restrict__ Wr, int* __restrict__ counts,
    int* __restrict__ tk_idx, float* __restrict__ tk_w) {
  int wid = threadIdx.x >> 6, lane = threadIdx.x & 63;
  int t = blockIdx.x * 4 + wid;
  const float* xr = x + (size_t)t * E_DIM;
  float xv[16];
#pragma unroll
  for (int i = 0; i < 16; ++i) xv[i] = xr[lane + 64 * i];
  float lg[8];
#pragma unroll
  for (int e = 0; e < 8; ++e) {
    const float* wr = Wr + e * E_DIM;
    float a = 0.f;
#pragma unroll
    for (int i = 0; i < 16; ++i) a += xv[i] * wr[lane + 64 * i];
#pragma unroll
    for (int o = 32; o; o >>= 1) a += __shfl_xor(a, o, 64);
    lg[e] = a;
  }
  if (lane == 0) {
    int i0 = 0; float l0 = lg[0];
#pragma unroll
    for (int e = 1; e < 8; ++e) if (lg[e] > l0) { l0 = lg[e]; i0 = e; }
    int i1 = -1; float l1 = -1e30f;
#pragma unroll
    for (int e = 0; e < 8; ++e) if (e != i0 && lg[e] > l1) { l1 = lg[e]; i1 = e; }
    float w0 = 1.f / (1.f + __expf(l1 - l0));
    atomicAdd(&counts[i0], 1);
    atomicAdd(&counts[i1], 1);
    tk_idx[2 * t]     = i0;  tk_idx[2 * t + 1] = i1;
    tk_w[2 * t]       = w0;  tk_w[2 * t + 1]   = 1.f - w0;
  }
}

// offsets + compact (expert, m0) tile table; parallel slot fill.
__global__ void offsets_k(const int* __restrict__ counts, int* __restrict__ offsets,
                          int* __restrict__ cursor,
                          int* __restrict__ slot_e, int* __restrict__ slot_m0) {
  __shared__ int cnt[NEXP], tbase[NEXP + 1];
  int tid = threadIdx.x;
  if (tid == 0) {
    int off = 0, tb = 0;
    for (int e = 0; e < NEXP; ++e) {
      int c = counts[e];
      cnt[e] = c;
      offsets[e] = off; cursor[e] = off; off += c;
      tbase[e] = tb; tb += (c + 127) >> 7;
    }
    tbase[NEXP] = tb;
  }
  __syncthreads();
  if (tid < NEXP) {
    int nt = (cnt[tid] + 127) >> 7, b = tbase[tid];
    for (int i = 0; i < nt; ++i) { slot_e[b + i] = tid; slot_m0[b + i] = i * 128; }
  }
  for (int s = tbase[NEXP] + tid; s < NSLOT; s += blockDim.x) {
    slot_e[s] = -1; slot_m0[s] = 0;
  }
}

__global__ __launch_bounds__(256) void scatter_k(const int* __restrict__ tk_idx,
    const float* __restrict__ tk_w, int* __restrict__ cursor,
    int* __restrict__ pair_token, float* __restrict__ pair_w, int* __restrict__ pair_pos) {
  int t = blockIdx.x * 256 + threadIdx.x;
#pragma unroll
  for (int k = 0; k < 2; ++k) {
    int e = tk_idx[2 * t + k];
    int pos = atomicAdd(&cursor[e], 1);
    pair_token[pos] = t;
    pair_w[pos] = tk_w[2 * t + k];
    pair_pos[2 * t + k] = pos;
  }
}

// ---------------- expert-sorted token rows: xs[p] = bf16(x[pair_token[p]]) ----------------
__global__ __launch_bounds__(256) void gatherx_k(const float* __restrict__ x,
    const int* __restrict__ pair_token, __hip_bfloat16* __restrict__ xs) {
  int p = blockIdx.x;
  int t = pair_token[p];
  const float* src = x + (size_t)t * E_DIM;
  __hip_bfloat16* dst = xs + (size_t)p * E_DIM;
  int i = threadIdx.x * 4;
  floatx4 v = *(const floatx4*)(src + i);
  union { __hip_bfloat16 h[4]; short4v s; } u;
#pragma unroll
  for (int j = 0; j < 4; ++j) u.h[j] = f2bf(v[j]);
  *(short4v*)(dst + i) = u.s;
}

// ------------- transpose + convert: in fp32 [R][C] -> out bf16 [Cpad][outRS] -------------
__global__ __launch_bounds__(256) void tcvt_k(const float* __restrict__ in,
    __hip_bfloat16* __restrict__ out, int R, int C, int outRS,
    size_t inExpStride, size_t outExpStride) {
  __shared__ float tile[64 * 65];
  int e = blockIdx.z;
  const float* ip = in + inExpStride * e;
  __hip_bfloat16* op = out + outExpStride * e;
  int c0 = blockIdx.x * 64, r0 = blockIdx.y * 64;
#pragma unroll
  for (int i = 0; i < 16; ++i) {
    int idx = i * 256 + threadIdx.x;
    int rr = idx >> 6, cc = idx & 63;
    int gr = r0 + rr, gc = c0 + cc;
    tile[rr * 65 + cc] = (gr < R && gc < C) ? ip[(size_t)gr * C + gc] : 0.f;
  }
  __syncthreads();
#pragma unroll
  for (int i = 0; i < 2; ++i) {
    int idx = i * 256 + threadIdx.x;
    int cc = idx >> 3, rb = (idx & 7) * 8;
    union { __hip_bfloat16 h[8]; intx4 v; } u;
#pragma unroll
    for (int j = 0; j < 8; ++j) u.h[j] = f2bf(tile[(rb + j) * 65 + cc]);
    *(intx4*)(op + (size_t)(c0 + cc) * outRS + (r0 + rb)) = u.v;
  }
}

// ---------------- GEMM1: h = silu(xs@Wv+bv) * (xs@Wg+bg) ----------------
// 128x128 block, 2x2 waves of 64x64, mfma_32x32x16, BK=32, register prefetch.
__global__ __launch_bounds__(256, 2) void gemm1_k(
    const __hip_bfloat16* __restrict__ xs,
    const int* __restrict__ counts, const int* __restrict__ offsets,
    const int* __restrict__ slot_e, const int* __restrict__ slot_m0,
    const float* __restrict__ bv, const float* __restrict__ bg,
    const __hip_bfloat16* __restrict__ WvT, const __hip_bfloat16* __restrict__ WgT,
    __hip_bfloat16* __restrict__ h) {
  int slot = blockIdx.y;
  int e = slot_e[slot];
  if (e < 0) return;
  int m0 = slot_m0[slot];
  int Me = counts[e], off = offsets[e];
  int n0 = blockIdx.x * 128;

  __shared__ __hip_bfloat16 sA[128 * 40];
  __shared__ __hip_bfloat16 sBv[128 * 40];
  __shared__ __hip_bfloat16 sBg[128 * 40];

  int tid = threadIdx.x;
  int wid = tid >> 6, lane = tid & 63;
  int wm = wid >> 1, wn = wid & 1;
  int l31 = lane & 31, q = lane >> 5;

  // staging: 4 lanes/row (16B each), rows srow and srow+64 per operand
  int srow = tid >> 2, sc = (tid & 3) * 8;
  const __hip_bfloat16* gA = xs + (size_t)(off + m0 + srow) * E_DIM + sc;
  size_t bb = (size_t)e * ((size_t)HP2 * E_DIM) + (size_t)(n0 + srow) * E_DIM + sc;
  const __hip_bfloat16* gBv = WvT + bb;
  const __hip_bfloat16* gBg = WgT + bb;
  const size_t rstep = (size_t)64 * E_DIM;

  floatx16 accv[2][2], accg[2][2];
#pragma unroll
  for (int mi = 0; mi < 2; ++mi)
#pragma unroll
    for (int ni = 0; ni < 2; ++ni) {
      accv[mi][ni] = (floatx16)(0.f);
      accg[mi][ni] = (floatx16)(0.f);
    }

  intx4 rA0, rA1, rV0, rV1, rG0, rG1;
  rA0 = *(const intx4*)(gA);          rA1 = *(const intx4*)(gA + rstep);
  rV0 = *(const intx4*)(gBv);         rV1 = *(const intx4*)(gBv + rstep);
  rG0 = *(const intx4*)(gBg);         rG1 = *(const intx4*)(gBg + rstep);

  const int NK = E_DIM / 32;
  for (int kt = 0; kt < NK; ++kt) {
    *(intx4*)(sA  + srow * 40 + sc) = rA0;  *(intx4*)(sA  + (srow + 64) * 40 + sc) = rA1;
    *(intx4*)(sBv + srow * 40 + sc) = rV0;  *(intx4*)(sBv + (srow + 64) * 40 + sc) = rV1;
    *(intx4*)(sBg + srow * 40 + sc) = rG0;  *(intx4*)(sBg + (srow + 64) * 40 + sc) = rG1;
    __syncthreads();
    if (kt + 1 < NK) {
      int k0 = (kt + 1) * 32;
      rA0 = *(const intx4*)(gA + k0);  rA1 = *(const intx4*)(gA + k0 + rstep);
      rV0 = *(const intx4*)(gBv + k0); rV1 = *(const intx4*)(gBv + k0 + rstep);
      rG0 = *(const intx4*)(gBg + k0); rG1 = *(const intx4*)(gBg + k0 + rstep);
    }
#pragma unroll
    for (int s = 0; s < 2; ++s) {
      int ko = s * 16 + q * 8;
      short8 a0 = *(const short8*)(sA + (wm * 64 + l31) * 40 + ko);
      short8 a1 = *(const short8*)(sA + (wm * 64 + 32 + l31) * 40 + ko);
      short8 v0 = *(const short8*)(sBv + (wn * 64 + l31) * 40 + ko);
      short8 v1 = *(const short8*)(sBv + (wn * 64 + 32 + l31) * 40 + ko);
      short8 g0 = *(const short8*)(sBg + (wn * 64 + l31) * 40 + ko);
      short8 g1 = *(const short8*)(sBg + (wn * 64 + 32 + l31) * 40 + ko);
      accv[0][0] = __builtin_amdgcn_mfma_f32_32x32x16_bf16(a0, v0, accv[0][0], 0, 0, 0);
      accv[0][1] = __builtin_amdgcn_mfma_f32_32x32x16_bf16(a0, v1, accv[0][1], 0, 0, 0);
      accv[1][0] = __builtin_amdgcn_mfma_f32_32x32x16_bf16(a1, v0, accv[1][0], 0, 0, 0);
      accv[1][1] = __builtin_amdgcn_mfma_f32_32x32x16_bf16(a1, v1, accv[1][1], 0, 0, 0);
      accg[0][0] = __builtin_amdgcn_mfma_f32_32x32x16_bf16(a0, g0, accg[0][0], 0, 0, 0);
      accg[0][1] = __builtin_amdgcn_mfma_f32_32x32x16_bf16(a0, g1, accg[0][1], 0, 0, 0);
      accg[1][0] = __builtin_amdgcn_mfma_f32_32x32x16_bf16(a1, g0, accg[1][0], 0, 0, 0);
      accg[1][1] = __builtin_amdgcn_mfma_f32_32x32x16_bf16(a1, g1, accg[1][1], 0, 0, 0);
    }
    __syncthreads();
  }

  // epilogue: bias + SwiGLU; store only n < HP (hbuf rows are HP wide)
#pragma unroll
  for (int ni = 0; ni < 2; ++ni) {
    int n = n0 + wn * 64 + ni * 32 + l31;
    float bvv = (n < HDIM) ? bv[e * HDIM + n] : 0.f;
    float bgv = (n < HDIM) ? bg[e * HDIM + n] : 0.f;
    bool nok = (n < HP);
#pragma unroll
    for (int mi = 0; mi < 2; ++mi) {
#pragma unroll
      for (int reg = 0; reg < 16; ++reg) {
        int row = (reg & 3) + 8 * (reg >> 2) + 4 * q;
        int m = m0 + wm * 64 + mi * 32 + row;
        if (m >= Me || !nok) continue;
        float hv = accv[mi][ni][reg] + bvv;
        float hg = accg[mi][ni][reg] + bgv;
        float sgm = 1.f / (1.f + __expf(-hv));
        h[(size_t)(off + m) * HP + n] = f2bf(hv * sgm * hg);
      }
    }
  }
}

// ---------------- GEMM2: pair_out = h @ Wo + bo ----------------
// 128x128 block, 2x2 waves of 64x64, mfma_32x32x16, BK=64, register prefetch.
__global__ __launch_bounds__(256, 2) void gemm2_k(
    const __hip_bfloat16* __restrict__ hb,
    const int* __restrict__ counts, const int* __restrict__ offsets,
    const int* __restrict__ slot_e, const int* __restrict__ slot_m0,
    const float* __restrict__ bo,
    const __hip_bfloat16* __restrict__ WoT,
    float* __restrict__ pout) {
  int slot = blockIdx.y;
  int e = slot_e[slot];
  if (e < 0) return;
  int m0 = slot_m0[slot];
  int Me = counts[e], off = offsets[e];
  int n0 = blockIdx.x * 128;

  __shared__ __hip_bfloat16 sA[128 * 72];
  __shared__ __hip_bfloat16 sB[128 * 72];

  int tid = threadIdx.x;
  int wid = tid >> 6, lane = tid & 63;
  int wm = wid >> 1, wn = wid & 1;
  int l31 = lane & 31, q = lane >> 5;

  // staging: 8 lanes/row (16B each), rows srow + {0,32,64,96}
  int srow = tid >> 3, sc = (tid & 7) * 8;
  const __hip_bfloat16* gA = hb + (size_t)(off + m0 + srow) * HP + sc;
  const __hip_bfloat16* gB =
      WoT + (size_t)e * ((size_t)E_DIM * HP) + (size_t)(n0 + srow) * HP + sc;
  const size_t rstep = (size_t)32 * HP;

  floatx16 acc[2][2];
#pragma unroll
  for (int mi = 0; mi < 2; ++mi)
#pragma unroll
    for (int ni = 0; ni < 2; ++ni) acc[mi][ni] = (floatx16)(0.f);

  intx4 rA[4], rB[4];
#pragma unroll
  for (int i = 0; i < 4; ++i) {
    rA[i] = *(const intx4*)(gA + (size_t)i * rstep);
    rB[i] = *(const intx4*)(gB + (size_t)i * rstep);
  }

  const int NK = HP / 64;
  for (int kt = 0; kt < NK; ++kt) {
#pragma unroll
    for (int i = 0; i < 4; ++i) {
      *(intx4*)(sA + (srow + i * 32) * 72 + sc) = rA[i];
      *(intx4*)(sB + (srow + i * 32) * 72 + sc) = rB[i];
    }
    __syncthreads();
    if (kt + 1 < NK) {
      int k0 = (kt + 1) * 64;
#pragma unroll
      for (int i = 0; i < 4; ++i) {
        rA[i] = *(const intx4*)(gA + k0 + (size_t)i * rstep);
        rB[i] = *(const intx4*)(gB + k0 + (size_t)i * rstep);
      }
    }
#pragma unroll
    for (int s = 0; s < 4; ++s) {
      int ko = s * 16 + q * 8;
      short8 a0 = *(const short8*)(sA + (wm * 64 + l31) * 72 + ko);
      short8 a1 = *(const short8*)(sA + (wm * 64 + 32 + l31) * 72 + ko);
      short8 b0 = *(const short8*)(sB + (wn * 64 + l31) * 72 + ko);
      short8 b1 = *(const short8*)(sB + (wn * 64 + 32 + l31) * 72 + ko);
      acc[0][0] = __builtin_amdgcn_mfma_f32_32x32x16_bf16(a0, b0, acc[0][0], 0, 0, 0);
      acc[0][1] = __builtin_amdgcn_mfma_f32_32x32x16_bf16(a0, b1, acc[0][1], 0, 0, 0);
      acc[1][0] = __builtin_amdgcn_mfma_f32_32x32x16_bf16(a1, b0, acc[1][0], 0, 0, 0);
      acc[1][1] = __builtin_amdgcn_mfma_f32_32x32x16_bf16(a1, b1, acc[1][1], 0, 0, 0);
    }
    __syncthreads();
  }

#pragma unroll
  for (int ni = 0; ni < 2; ++ni) {
    int n = n0 + wn * 64 + ni * 32 + l31;
    float bb = bo[e * E_DIM + n];
#pragma unroll
    for (int mi = 0; mi < 2; ++mi) {
#pragma unroll
      for (int reg = 0; reg < 16; ++reg) {
        int row = (reg & 3) + 8 * (reg >> 2) + 4 * q;
        int m = m0 + wm * 64 + mi * 32 + row;
        if (m >= Me) continue;
        pout[(size_t)(off + m) * E_DIM + n] = acc[mi][ni][reg] + bb;
      }
    }
  }
}

// ---------------- combine + residual + LayerNorm ----------------
__global__ __launch_bounds__(256) void ln_k(const float* __restrict__ x,
    const float* __restrict__ pout, const int* __restrict__ pair_pos,
    const float* __restrict__ pair_w, const float* __restrict__ ln_g,
    const float* __restrict__ ln_b, float* __restrict__ out) {
  int t = blockIdx.x, tid = threadIdx.x;
  int p0 = pair_pos[2 * t], p1 = pair_pos[2 * t + 1];
  float w0 = pair_w[p0], w1 = pair_w[p1];
  const float* xr = x + (size_t)t * E_DIM;
  const float* r0 = pout + (size_t)p0 * E_DIM;
  const float* r1 = pout + (size_t)p1 * E_DIM;
  float y[4];
  float s = 0.f, ss = 0.f;
#pragma unroll
  for (int i = 0; i < 4; ++i) {
    int e = tid + 256 * i;
    y[i] = xr[e] + w0 * r0[e] + w1 * r1[e];
    s += y[i];
    ss += y[i] * y[i];
  }
#pragma unroll
  for (int o = 32; o; o >>= 1) { s += __shfl_xor(s, o, 64); ss += __shfl_xor(ss, o, 64); }
  __shared__ float red[8];
  int wid = tid >> 6, lane = tid & 63;
  if (lane == 0) { red[wid] = s; red[4 + wid] = ss; }
  __syncthreads();
  s  = red[0] + red[1] + red[2] + red[3];
  ss = red[4] + red[5] + red[6] + red[7];
  float mu = s * (1.f / E_DIM);
  float var = ss * (1.f / E_DIM) - mu * mu;
  float rs = rsqrtf(var + LN_EPS);
#pragma unroll
  for (int i = 0; i < 4; ++i) {
    int e = tid + 256 * i;
    out[(size_t)t * E_DIM + e] = ln_g[e] * (y[i] - mu) * rs + ln_b[e];
  }
}

extern "C" void kernel_launch(void* const* d_in, const int* in_sizes, int n_in,
                              void* d_out, int out_size, void* d_ws, size_t ws_size,
                              hipStream_t stream) {
  const float* x    = (const float*)d_in[0];
  const float* Wr   = (const float*)d_in[1];
  const float* Wv   = (const float*)d_in[2];
  const float* bv   = (const float*)d_in[3];
  const float* Wg   = (const float*)d_in[4];
  const float* bg   = (const float*)d_in[5];
  const float* Wo   = (const float*)d_in[6];
  const float* bo   = (const float*)d_in[7];
  const float* ln_g = (const float*)d_in[8];
  const float* ln_b = (const float*)d_in[9];
  float* out = (float*)d_out;

  char* ws = (char*)d_ws;
  size_t off = 0;
  auto alloc = [&](size_t bytes) -> void* {
    void* p = ws + off;
    off = (off + bytes + 255) & ~(size_t)255;
    return p;
  };
  int*   counts     = (int*)alloc(32);
  int*   cursor     = (int*)alloc(32);
  int*   offsets    = (int*)alloc(32);
  int*   slot_e     = (int*)alloc(NSLOT * 4);
  int*   slot_m0    = (int*)alloc(NSLOT * 4);
  int*   tk_idx     = (int*)alloc((size_t)NTOK * 2 * 4);
  float* tk_w       = (float*)alloc((size_t)NTOK * 2 * 4);
  int*   pair_token = (int*)alloc((size_t)NPAIR * 4);
  float* pair_w     = (float*)alloc((size_t)NPAIR * 4);
  int*   pair_pos   = (int*)alloc((size_t)NPAIR * 4);
  // xs (bf16, live until gemm1) and pout (fp32, live from gemm2) share one region
  size_t xs_bytes   = (size_t)(NPAIR + 128) * E_DIM * 2;
  size_t pout_bytes = (size_t)NPAIR * E_DIM * 4;
  char*  xs_pout    = (char*)alloc(xs_bytes > pout_bytes ? xs_bytes : pout_bytes);
  __hip_bfloat16* xs = (__hip_bfloat16*)xs_pout;
  float* pout        = (float*)xs_pout;
  __hip_bfloat16* hbuf = (__hip_bfloat16*)alloc((size_t)(NPAIR + 128) * HP * 2);

  __hip_bfloat16* WvT = (__hip_bfloat16*)alloc((size_t)NEXP * HP2 * E_DIM * 2);
  __hip_bfloat16* WgT = (__hip_bfloat16*)alloc((size_t)NEXP * HP2 * E_DIM * 2);
  __hip_bfloat16* WoT = (__hip_bfloat16*)alloc((size_t)NEXP * E_DIM * HP * 2);

  hipMemsetAsync(d_ws, 0, 1024, stream);  // counts / cursor / offsets / slots

  router_k<<<NTOK / 4, 256, 0, stream>>>(x, Wr, counts, tk_idx, tk_w);
  offsets_k<<<1, 64, 0, stream>>>(counts, offsets, cursor, slot_e, slot_m0);
  scatter_k<<<NTOK / 256, 256, 0, stream>>>(tk_idx, tk_w, cursor, pair_token, pair_w, pair_pos);
  gatherx_k<<<NPAIR, 256, 0, stream>>>(x, pair_token, xs);

  // Wv,Wg: fp32 [1024][2730] -> bf16 [2816][1024]
  tcvt_k<<<dim3(HP2 / 64, E_DIM / 64, NEXP), 256, 0, stream>>>(
      Wv, WvT, E_DIM, HDIM, E_DIM, (size_t)E_DIM * HDIM, (size_t)HP2 * E_DIM);
  tcvt_k<<<dim3(HP2 / 64, E_DIM / 64, NEXP), 256, 0, stream>>>(
      Wg, WgT, E_DIM, HDIM, E_DIM, (size_t)E_DIM * HDIM, (size_t)HP2 * E_DIM);
  // Wo: fp32 [2730][1024] -> bf16 [1024][2752]
  tcvt_k<<<dim3(E_DIM / 64, HP / 64, NEXP), 256, 0, stream>>>(
      Wo, WoT, HDIM, E_DIM, HP, (size_t)HDIM * E_DIM, (size_t)E_DIM * HP);

  gemm1_k<<<dim3(HP2 / 128, NSLOT), 256, 0, stream>>>(
      xs, counts, offsets, slot_e, slot_m0, bv, bg, WvT, WgT, hbuf);
  gemm2_k<<<dim3(E_DIM / 128, NSLOT), 256, 0, stream>>>(
      hbuf, counts, offsets, slot_e, slot_m0, bo, WoT, pout);

  ln_k<<<NTOK, 256, 0, stream>>>(x, pout, pair_pos, pair_w, ln_g, ln_b, out);
}